// Round 4
// baseline (226.571 us; speedup 1.0000x reference)
//
#include <hip/hip_runtime.h>
#include <hip/hip_fp16.h>

#define FDIM 32
#define BSH 7                 // 128 nodes per bucket
#define BNODES 128
#define NBMAX 1024            // max buckets (N <= 131072)
#define CHUNK 8192            // edges per partition chunk (391 chunks at E=3.2M)
#define NCMAX 512             // max chunks (E <= 4.19M)
#define RCAP 4608             // per-bucket record cap (mean 4096, +8 sigma)
#define SCAP 5120             // ssrec cap: RCAP + 128*4-alignment padding headroom

typedef unsigned int u32;
typedef unsigned short u16;

#define BFLO(u) __uint_as_float((u) << 16)
#define BFHI(u) __uint_as_float((u) & 0xFFFF0000u)

union HCV { __half h; u16 u; };
__device__ __forceinline__ u16 f32_f16b(float f) { HCV c; c.h = __float2half(f); return c.u; }
__device__ __forceinline__ float f16b_f32(u32 b) { HCV c; c.u = (u16)b; return __half2float(c.h); }

__device__ __forceinline__ void acc8(float4& p0, float4& p1, float w, uint4 h) {
    p0.x = fmaf(w, BFLO(h.x), p0.x);
    p0.y = fmaf(w, BFHI(h.x), p0.y);
    p0.z = fmaf(w, BFLO(h.y), p0.z);
    p0.w = fmaf(w, BFHI(h.y), p0.w);
    p1.x = fmaf(w, BFLO(h.z), p1.x);
    p1.y = fmaf(w, BFHI(h.z), p1.y);
    p1.z = fmaf(w, BFLO(h.w), p1.z);
    p1.w = fmaf(w, BFHI(h.w), p1.w);
}

// ---------------- k1b: partition; LDS-staged scatter -> fully-coalesced streamout ----------------
// round-1 lesson: k1b is VMEM-scatter-bound (VALUBusy 1.3%). Stage the bucket-sorted chunk
// in LDS (48 KB), then write rkey/rwh with dwordx4 coalesced streams. 1024-thr blocks are
// wave-capped at 2 blocks/CU, so 52 KB LDS costs no occupancy.
__global__ __launch_bounds__(1024, 8) void k1b(const int* __restrict__ srcs,
                                               const int* __restrict__ dsts,
                                               const float* __restrict__ ew,
                                               u32* __restrict__ offsT,
                                               u32* __restrict__ rkey,
                                               u16* __restrict__ rwh,
                                               int E, int NB, int nch) {
    __shared__ __align__(16) u32 skey[CHUNK];   // 32 KB
    __shared__ __align__(16) u16 swv[CHUNK];    // 16 KB
    __shared__ u32 lh[NBMAX];                   // 4 KB
    __shared__ u32 wsum[16];
    int t = threadIdx.x, c = blockIdx.x;
    int base = c * CHUNK;
    int end = base + CHUNK; if (end > E) end = E;
    int nloc = end - base;
    int i0 = t * 8;
    bool full = (i0 + 8 <= nloc);
    int sv[8], dv[8];
    float wv[8];
    u32 rk[8];
    // hoist ALL loads before the histogram (latency overlap)
    if (full) {
        int4 a  = ((const int4*)(srcs + base))[t * 2];
        int4 b2 = ((const int4*)(srcs + base))[t * 2 + 1];
        int4 d0 = ((const int4*)(dsts + base))[t * 2];
        int4 d1 = ((const int4*)(dsts + base))[t * 2 + 1];
        float4 w0 = ((const float4*)(ew + base))[t * 2];
        float4 w1 = ((const float4*)(ew + base))[t * 2 + 1];
        sv[0]=a.x; sv[1]=a.y; sv[2]=a.z; sv[3]=a.w; sv[4]=b2.x; sv[5]=b2.y; sv[6]=b2.z; sv[7]=b2.w;
        dv[0]=d0.x; dv[1]=d0.y; dv[2]=d0.z; dv[3]=d0.w; dv[4]=d1.x; dv[5]=d1.y; dv[6]=d1.z; dv[7]=d1.w;
        wv[0]=w0.x; wv[1]=w0.y; wv[2]=w0.z; wv[3]=w0.w; wv[4]=w1.x; wv[5]=w1.y; wv[6]=w1.z; wv[7]=w1.w;
    } else {
#pragma unroll
        for (int k = 0; k < 8; ++k) {
            int i = i0 + k;
            bool v = i < nloc;
            sv[k] = v ? srcs[base + i] : 0;
            dv[k] = v ? dsts[base + i] : 0;
            wv[k] = v ? ew[base + i] : 0.f;
        }
    }
    for (int i = t; i < NB; i += 1024) lh[i] = 0u;
    __syncthreads();
    if (full) {
#pragma unroll
        for (int k = 0; k < 8; ++k) rk[k] = atomicAdd(&lh[sv[k] >> BSH], 1u);
    } else {
#pragma unroll
        for (int k = 0; k < 8; ++k) {
            bool v = (i0 + k) < nloc;
            rk[k] = v ? atomicAdd(&lh[sv[k] >> BSH], 1u) : 0u;
        }
    }
    __syncthreads();
    // shfl-based inclusive scan over NB bucket counts
    int lane = t & 63, w = t >> 6;
    u32 v = (t < NB) ? lh[t] : 0u;
    u32 inc = v;
#pragma unroll
    for (int d = 1; d < 64; d <<= 1) {
        u32 o = __shfl_up(inc, (unsigned)d, 64);
        if (lane >= d) inc += o;
    }
    if (lane == 63) wsum[w] = inc;
    __syncthreads();
    u32 woff = 0;
    for (int i = 0; i < w; ++i) woff += wsum[i];
    inc += woff;
    u32 ex = inc - v;
    if (t < NB) { offsT[(size_t)t * nch + c] = ex; lh[t] = ex; }
    if (t == 0) offsT[(size_t)NB * nch + c] = (u32)nloc;
    __syncthreads();
    // atomic-free placement into LDS: pos = bucket_exclusive + rank
    if (full) {
#pragma unroll
        for (int k = 0; k < 8; ++k) {
            int s = sv[k];
            u32 pos = lh[s >> BSH] + rk[k];
            skey[pos] = ((u32)(s & (BNODES - 1)) << 17) | (u32)dv[k];
            swv[pos] = f32_f16b(wv[k]);          // w in [0,1): fp16, sign bit 0
        }
    } else {
#pragma unroll
        for (int k = 0; k < 8; ++k) {
            if ((i0 + k) < nloc) {
                int s = sv[k];
                u32 pos = lh[s >> BSH] + rk[k];
                skey[pos] = ((u32)(s & (BNODES - 1)) << 17) | (u32)dv[k];
                swv[pos] = f32_f16b(wv[k]);
            }
        }
    }
    __syncthreads();
    // coalesced streamout (tail beyond nloc is never read downstream — garbage ok)
    ((uint4*)(rkey + (size_t)base))[t]        = ((const uint4*)skey)[t];
    ((uint4*)(rkey + (size_t)base))[t + 1024] = ((const uint4*)skey)[t + 1024];
    ((uint4*)(rwh + (size_t)base))[t]         = ((const uint4*)swv)[t];
}

// ---------------- k_nh: runid inverse-map key histogram + reg-cached GEMM ----------------
__global__ __launch_bounds__(512) void k_nh(const u32* __restrict__ rkey,
                                            const u32* __restrict__ offsT,
                                            const float* __restrict__ feat,
                                            const float* __restrict__ kern,
                                            u16* __restrict__ hsb,
                                            u32* __restrict__ nodemeta,
                                            int N, int NB, int nch) {
    __shared__ float skern[FDIM * FDIM];
    __shared__ float sfeat[BNODES * FDIM];
    __shared__ u32 sbase[NCMAX];
    __shared__ u16 runid[RCAP];
    __shared__ u32 lcnt[BNODES];
    __shared__ float lnorm[BNODES];
    __shared__ u32 wsum[8];
    __shared__ u32 ws2[2];
    __shared__ u32 stot;
    int b = blockIdx.x, t = threadIdx.x;
    for (int i = t; i < FDIM * FDIM / 4; i += 512) ((float4*)skern)[i] = ((const float4*)kern)[i];
    int base_n = b << BSH;
    int base_nf = base_n * FDIM;
    int lim = N * FDIM - base_nf; if (lim > BNODES * FDIM) lim = BNODES * FDIM;
    for (int i = t; i < (lim >> 2); i += 512) ((float4*)sfeat)[i] = ((const float4*)(feat + base_nf))[i];
    if (t < BNODES) lcnt[t] = 0u;
    u32 rl = 0u, s0 = 0u;
    if (t < nch) {
        s0 = offsT[(size_t)b * nch + t];             // coalesced row read
        rl = offsT[(size_t)(b + 1) * nch + t] - s0;  // coalesced row read
    }
    int lane = t & 63, w = t >> 6;
    u32 inc = rl;
#pragma unroll
    for (int d = 1; d < 64; d <<= 1) {
        u32 o = __shfl_up(inc, (unsigned)d, 64);
        if (lane >= d) inc += o;
    }
    if (lane == 63) wsum[w] = inc;
    __syncthreads();
    u32 woff = 0;
    for (int i = 0; i < w; ++i) woff += wsum[i];
    inc += woff;
    // inverse map: run r owns records [pl0, pl0+rl) -> runid[]; sbase folds per-run consts
    if (t < nch) {
        u32 pl0 = inc - rl;
        sbase[t] = (u32)t * CHUNK + s0 - pl0;
        u32 p = pl0 < RCAP ? pl0 : RCAP;
        u32 e = pl0 + rl; if (e > RCAP) e = RCAP;
        for (; p < e; ++p) runid[p] = (u16)t;
    }
    if (t == nch - 1) stot = inc;
    __syncthreads();
    u32 tot = stot; if (tot > RCAP) tot = RCAP;
    // histogram: 8 statically-unrolled independent chains
    {
        u32 keyv[8]; bool val[8];
#pragma unroll
        for (int i = 0; i < 8; ++i) {
            u32 g = (u32)t + ((u32)i << 9);
            val[i] = g < tot;
            keyv[i] = 0u;
            if (val[i]) {
                int r = runid[g];
                keyv[i] = rkey[(size_t)(sbase[r] + g)];
            }
        }
#pragma unroll
        for (int i = 0; i < 8; ++i)
            if (val[i]) atomicAdd(&lcnt[keyv[i] >> 17], 1u);
        for (u32 g = (u32)t + 4096u; g < tot; g += 512u) {
            int r = runid[g];
            atomicAdd(&lcnt[rkey[(size_t)(sbase[r] + g)] >> 17], 1u);
        }
    }
    __syncthreads();
    // nodemeta: 4-record-aligned exclusive offsets (16 B ssrec alignment for b128 reads)
    u32 d = 0u, pad = 0u, inc2 = 0u;
    if (t < BNODES) {
        d = lcnt[t];
        pad = (d + 3u) & ~3u;
        inc2 = pad;
    }
    if (t < 128) {
#pragma unroll
        for (int dd = 1; dd < 64; dd <<= 1) {
            u32 o = __shfl_up(inc2, (unsigned)dd, 64);
            if ((t & 63) >= dd) inc2 += o;
        }
        if ((t & 63) == 63) ws2[t >> 6] = inc2;
    }
    __syncthreads();
    if (t < 128) {
        if (t >= 64) inc2 += ws2[0];
        u32 ex = inc2 - pad;
        lnorm[t] = rsqrtf(fmaxf((float)d, 1.0f));
        int n = base_n + t;
        if (n < N) nodemeta[n] = ex | (d << 16);
    }
    __syncthreads();
    // GEMM: skern column cached in 32 registers, sfeat rows as float4
    int f = t & 31, g8 = t >> 5;
    float kc[FDIM];
#pragma unroll
    for (int k = 0; k < FDIM; ++k) kc[k] = skern[k * FDIM + f];
#pragma unroll
    for (int k8 = 0; k8 < 8; ++k8) {
        int nl = g8 * 8 + k8;
        int n = base_n + nl;
        const float4* fr = (const float4*)(sfeat + nl * FDIM);
        float4 rr[8];
#pragma unroll
        for (int q = 0; q < 8; ++q) rr[q] = fr[q];
        float acc = 0.f;
#pragma unroll
        for (int q = 0; q < 8; ++q) {
            acc = fmaf(rr[q].x, kc[4 * q + 0], acc);
            acc = fmaf(rr[q].y, kc[4 * q + 1], acc);
            acc = fmaf(rr[q].z, kc[4 * q + 2], acc);
            acc = fmaf(rr[q].w, kc[4 * q + 3], acc);
        }
        float x = lnorm[nl] * acc;
        u32 u = __float_as_uint(x);
        u = (u + 0x7FFFu + ((u >> 16) & 1u)) >> 16;   // RNE f32 -> bf16
        if (n < N) hsb[(size_t)n * FDIM + f] = (u16)u;
    }
}

// ---------------- k2: packed-u32 ssrec (dst:17|w_fp16:15); 4 blocks/CU; 8-wide gather ----------------
__global__ __launch_bounds__(512, 8) void k2(const u32* __restrict__ rkey,
                                             const u16* __restrict__ rwh,
                                             const u32* __restrict__ offsT,
                                             const u32* __restrict__ nodemeta,
                                             const u16* __restrict__ hsb,
                                             const float* __restrict__ bias,
                                             float* __restrict__ out,
                                             int N, int NB, int nch) {
    __shared__ __align__(16) u32 ssrec[SCAP];   // 20 KB packed node-sorted records
    __shared__ u32 sbase[NCMAX];
    __shared__ u16 runid[RCAP];
    __shared__ u32 loff[BNODES];
    __shared__ u32 lcnt[BNODES];
    __shared__ u32 lcur[BNODES];
    __shared__ u32 snode[BNODES];
    __shared__ u32 lbin[128];
    __shared__ u32 wsum[8];
    __shared__ u32 ws2[2];
    __shared__ u32 stot;
    int b = blockIdx.x, t = threadIdx.x;
    int base_n = b << BSH;
    if (t < BNODES) {
        int n = base_n + t;
        u32 m = (n < N) ? nodemeta[n] : 0u;
        loff[t] = m & 0xFFFFu;
        lcnt[t] = m >> 16;
        lcur[t] = m & 0xFFFFu;
    }
    if (t < 128) lbin[t] = 0u;
    u32 rl = 0u, s0 = 0u;
    if (t < nch) {
        s0 = offsT[(size_t)b * nch + t];
        rl = offsT[(size_t)(b + 1) * nch + t] - s0;
    }
    int lane = t & 63, w = t >> 6;
    u32 inc = rl;
#pragma unroll
    for (int d = 1; d < 64; d <<= 1) {
        u32 o = __shfl_up(inc, (unsigned)d, 64);
        if (lane >= d) inc += o;
    }
    if (lane == 63) wsum[w] = inc;
    __syncthreads();
    u32 woff = 0;
    for (int i = 0; i < w; ++i) woff += wsum[i];
    inc += woff;
    if (t < nch) {
        u32 pl0 = inc - rl;
        sbase[t] = (u32)t * CHUNK + s0 - pl0;
        u32 p = pl0 < RCAP ? pl0 : RCAP;
        u32 e = pl0 + rl; if (e > RCAP) e = RCAP;
        for (; p < e; ++p) runid[p] = (u16)t;
    }
    if (t == nch - 1) stot = inc;
    __syncthreads();
    u32 tot = stot; if (tot > RCAP) tot = RCAP;
    // scatter: 8 independent load chains (rkey + rwh), pack to u32, LDS node-sort
    {
        u32 keyv[8], whv[8]; bool val[8];
#pragma unroll
        for (int i = 0; i < 8; ++i) {
            u32 g = (u32)t + ((u32)i << 9);
            val[i] = g < tot;
            keyv[i] = 0u; whv[i] = 0u;
            if (val[i]) {
                int r = runid[g];
                u32 idx = sbase[r] + g;
                keyv[i] = rkey[(size_t)idx];
                whv[i] = rwh[(size_t)idx];
            }
        }
#pragma unroll
        for (int i = 0; i < 8; ++i) {
            if (val[i]) {
                u32 pos = atomicAdd(&lcur[keyv[i] >> 17], 1u);
                if (pos < SCAP) ssrec[pos] = ((keyv[i] & 0x1FFFFu) << 15) | (whv[i] & 0x7FFFu);
            }
        }
        for (u32 g = (u32)t + 4096u; g < tot; g += 512u) {
            int r = runid[g];
            u32 idx = sbase[r] + g;
            u32 key = rkey[(size_t)idx];
            u32 wh = rwh[(size_t)idx];
            u32 pos = atomicAdd(&lcur[key >> 17], 1u);
            if (pos < SCAP) ssrec[pos] = ((key & 0x1FFFFu) << 15) | (wh & 0x7FFFu);
        }
    }
    // degree counting-sort (128 bins) for wave load balance
    if (t < BNODES) {
        u32 len = lcnt[t];
        atomicAdd(&lbin[len > 127u ? 127u : len], 1u);
    }
    __syncthreads();
    u32 bv_ = 0u, binc = 0u;
    if (t < 128) {
        bv_ = lbin[t];
        binc = bv_;
#pragma unroll
        for (int dd = 1; dd < 64; dd <<= 1) {
            u32 o = __shfl_up(binc, (unsigned)dd, 64);
            if ((t & 63) >= dd) binc += o;
        }
        if ((t & 63) == 63) ws2[t >> 6] = binc;
    }
    __syncthreads();
    if (t < 128) {
        if (t >= 64) binc += ws2[0];
        lbin[t] = binc - bv_;                        // exclusive
    }
    __syncthreads();
    if (t < BNODES) {
        u32 len = lcnt[t];
        u32 pos = atomicAdd(&lbin[len > 127u ? 127u : len], 1u);
        snode[pos] = (u32)t;
    }
    __syncthreads();
    // gather: 128 groups of 4 lanes; lane l = features 8l..8l+7; 8 records per 2 b128 LDS reads
    int l = t & 3, g = t >> 2;
    u32 nl = snode[g];
    int n = base_n + (int)nl;
    u32 off = loff[nl];                  // multiple of 4 -> 16 B aligned
    u32 len = lcnt[nl];
    float ns = rsqrtf(fmaxf((float)len, 1.0f));
    const uint4* hp4 = (const uint4*)hsb;           // row n: hp4[n*4 + l]
    float4 bv0 = ((const float4*)bias)[2 * l];
    float4 bv1 = ((const float4*)bias)[2 * l + 1];
    float4 x0 = make_float4(0.f, 0.f, 0.f, 0.f), x1 = make_float4(0.f, 0.f, 0.f, 0.f);
    float4 y0 = make_float4(0.f, 0.f, 0.f, 0.f), y1 = make_float4(0.f, 0.f, 0.f, 0.f);
    u32 j = 0;
    for (; j + 8 <= len; j += 8) {
        uint4 a = *(const uint4*)(ssrec + off + j);        // rec j..j+3
        uint4 c = *(const uint4*)(ssrec + off + j + 4);    // rec j+4..j+7
        uint4 h0 = hp4[(size_t)(a.x >> 15) * 4 + l];
        uint4 h1 = hp4[(size_t)(a.y >> 15) * 4 + l];
        uint4 h2 = hp4[(size_t)(a.z >> 15) * 4 + l];
        uint4 h3 = hp4[(size_t)(a.w >> 15) * 4 + l];
        uint4 h4 = hp4[(size_t)(c.x >> 15) * 4 + l];
        uint4 h5 = hp4[(size_t)(c.y >> 15) * 4 + l];
        uint4 h6 = hp4[(size_t)(c.z >> 15) * 4 + l];
        uint4 h7 = hp4[(size_t)(c.w >> 15) * 4 + l];
        acc8(x0, x1, f16b_f32(a.x & 0x7FFFu), h0);
        acc8(y0, y1, f16b_f32(a.y & 0x7FFFu), h1);
        acc8(x0, x1, f16b_f32(a.z & 0x7FFFu), h2);
        acc8(y0, y1, f16b_f32(a.w & 0x7FFFu), h3);
        acc8(x0, x1, f16b_f32(c.x & 0x7FFFu), h4);
        acc8(y0, y1, f16b_f32(c.y & 0x7FFFu), h5);
        acc8(x0, x1, f16b_f32(c.z & 0x7FFFu), h6);
        acc8(y0, y1, f16b_f32(c.w & 0x7FFFu), h7);
    }
    for (; j + 4 <= len; j += 4) {
        uint4 a = *(const uint4*)(ssrec + off + j);
        uint4 h0 = hp4[(size_t)(a.x >> 15) * 4 + l];
        uint4 h1 = hp4[(size_t)(a.y >> 15) * 4 + l];
        uint4 h2 = hp4[(size_t)(a.z >> 15) * 4 + l];
        uint4 h3 = hp4[(size_t)(a.w >> 15) * 4 + l];
        acc8(x0, x1, f16b_f32(a.x & 0x7FFFu), h0);
        acc8(y0, y1, f16b_f32(a.y & 0x7FFFu), h1);
        acc8(x0, x1, f16b_f32(a.z & 0x7FFFu), h2);
        acc8(y0, y1, f16b_f32(a.w & 0x7FFFu), h3);
    }
    for (; j < len; ++j) {
        u32 q = ssrec[off + j];
        uint4 h = hp4[(size_t)(q >> 15) * 4 + l];
        acc8(x0, x1, f16b_f32(q & 0x7FFFu), h);
    }
    if (n < N) {
        float4 r0, r1;
        r0.x = fmaf(ns, x0.x + y0.x, bv0.x);
        r0.y = fmaf(ns, x0.y + y0.y, bv0.y);
        r0.z = fmaf(ns, x0.z + y0.z, bv0.z);
        r0.w = fmaf(ns, x0.w + y0.w, bv0.w);
        r1.x = fmaf(ns, x1.x + y1.x, bv1.x);
        r1.y = fmaf(ns, x1.y + y1.y, bv1.y);
        r1.z = fmaf(ns, x1.z + y1.z, bv1.z);
        r1.w = fmaf(ns, x1.w + y1.w, bv1.w);
        ((float4*)(out + (size_t)n * FDIM))[2 * l] = r0;
        ((float4*)(out + (size_t)n * FDIM))[2 * l + 1] = r1;
    }
}

extern "C" void kernel_launch(void* const* d_in, const int* in_sizes, int n_in,
                              void* d_out, int out_size, void* d_ws, size_t ws_size,
                              hipStream_t stream) {
    const float* feat = (const float*)d_in[0];
    const int*   srcs = (const int*)d_in[1];
    const int*   dsts = (const int*)d_in[2];
    const float* ew   = (const float*)d_in[3];
    const float* kern = (const float*)d_in[4];
    const float* bias = (const float*)d_in[5];
    float* out = (float*)d_out;

    int N = in_sizes[0] / FDIM;
    int E = in_sizes[1];
    int NB = (N + BNODES - 1) >> BSH;        // 782 for N=100000; <= NBMAX
    int nchunks = (E + CHUNK - 1) / CHUNK;   // 391; <= NCMAX

    // workspace layout (~27 MB)
    char* w = (char*)d_ws;
    u16* hsb      = (u16*)w;   w += (((size_t)N * FDIM * sizeof(u16) + 15) & ~15ull);     // 6.4 MB
    u32* rkey     = (u32*)w;   w += (size_t)nchunks * CHUNK * sizeof(u32);                // 12.8 MB
    u16* rwh      = (u16*)w;   w += (((size_t)nchunks * CHUNK * sizeof(u16) + 15) & ~15ull); // 6.4 MB
    u32* offsT    = (u32*)w;   w += (size_t)(NB + 1) * nchunks * sizeof(u32);             // 1.2 MB
    u32* nodemeta = (u32*)w;   w += (size_t)N * sizeof(u32);                              // 0.4 MB

    k1b<<<nchunks, 1024, 0, stream>>>(srcs, dsts, ew, offsT, rkey, rwh, E, NB, nchunks);
    k_nh<<<NB, 512, 0, stream>>>(rkey, offsT, feat, kern, hsb, nodemeta, N, NB, nchunks);
    k2<<<NB, 512, 0, stream>>>(rkey, rwh, offsT, nodemeta, hsb, bias, out, N, NB, nchunks);
}

// Round 5
// 184.170 us; speedup vs baseline: 1.2302x; 1.2302x over previous
//
#include <hip/hip_runtime.h>
#include <hip/hip_fp16.h>

#define FDIM 32
#define BSH 7                 // 128 nodes per bucket
#define BNODES 128
#define NBMAX 1024            // max buckets (N <= 131072)
#define CHUNK 8192            // edges per partition chunk (391 chunks at E=3.2M)
#define NCMAX 512             // max chunks (E <= 4.19M)
#define RCAP 4608             // per-bucket record cap (mean 4096, +8 sigma)
#define SCAP 5120             // ssrec cap: RCAP + 128*4-alignment padding headroom

typedef unsigned int u32;
typedef unsigned short u16;

#define BFLO(u) __uint_as_float((u) << 16)
#define BFHI(u) __uint_as_float((u) & 0xFFFF0000u)

union HCV { __half h; u16 u; };
__device__ __forceinline__ u16 f32_f16b(float f) { HCV c; c.h = __float2half(f); return c.u; }
__device__ __forceinline__ float f16b_f32(u32 b) { HCV c; c.u = (u16)b; return __half2float(c.h); }

__device__ __forceinline__ void acc8(float4& p0, float4& p1, float w, uint4 h) {
    p0.x = fmaf(w, BFLO(h.x), p0.x);
    p0.y = fmaf(w, BFHI(h.x), p0.y);
    p0.z = fmaf(w, BFLO(h.y), p0.z);
    p0.w = fmaf(w, BFHI(h.y), p0.w);
    p1.x = fmaf(w, BFLO(h.z), p1.x);
    p1.y = fmaf(w, BFHI(h.z), p1.y);
    p1.z = fmaf(w, BFLO(h.w), p1.z);
    p1.w = fmaf(w, BFHI(h.w), p1.w);
}

// ---------------- k1b: partition; LDS-staged scatter -> fully-coalesced streamout ----------------
__global__ __launch_bounds__(1024, 8) void k1b(const int* __restrict__ srcs,
                                               const int* __restrict__ dsts,
                                               const float* __restrict__ ew,
                                               u32* __restrict__ offsT,
                                               u32* __restrict__ rkey,
                                               u16* __restrict__ rwh,
                                               int E, int NB, int nch) {
    __shared__ __align__(16) u32 skey[CHUNK];   // 32 KB
    __shared__ __align__(16) u16 swv[CHUNK];    // 16 KB
    __shared__ u32 lh[NBMAX];                   // 4 KB
    __shared__ u32 wsum[16];
    int t = threadIdx.x, c = blockIdx.x;
    int base = c * CHUNK;
    int end = base + CHUNK; if (end > E) end = E;
    int nloc = end - base;
    int i0 = t * 8;
    bool full = (i0 + 8 <= nloc);
    int sv[8], dv[8];
    float wv[8];
    u32 rk[8];
    // hoist ALL loads before the histogram (latency overlap)
    if (full) {
        int4 a  = ((const int4*)(srcs + base))[t * 2];
        int4 b2 = ((const int4*)(srcs + base))[t * 2 + 1];
        int4 d0 = ((const int4*)(dsts + base))[t * 2];
        int4 d1 = ((const int4*)(dsts + base))[t * 2 + 1];
        float4 w0 = ((const float4*)(ew + base))[t * 2];
        float4 w1 = ((const float4*)(ew + base))[t * 2 + 1];
        sv[0]=a.x; sv[1]=a.y; sv[2]=a.z; sv[3]=a.w; sv[4]=b2.x; sv[5]=b2.y; sv[6]=b2.z; sv[7]=b2.w;
        dv[0]=d0.x; dv[1]=d0.y; dv[2]=d0.z; dv[3]=d0.w; dv[4]=d1.x; dv[5]=d1.y; dv[6]=d1.z; dv[7]=d1.w;
        wv[0]=w0.x; wv[1]=w0.y; wv[2]=w0.z; wv[3]=w0.w; wv[4]=w1.x; wv[5]=w1.y; wv[6]=w1.z; wv[7]=w1.w;
    } else {
#pragma unroll
        for (int k = 0; k < 8; ++k) {
            int i = i0 + k;
            bool v = i < nloc;
            sv[k] = v ? srcs[base + i] : 0;
            dv[k] = v ? dsts[base + i] : 0;
            wv[k] = v ? ew[base + i] : 0.f;
        }
    }
    for (int i = t; i < NB; i += 1024) lh[i] = 0u;
    __syncthreads();
    if (full) {
#pragma unroll
        for (int k = 0; k < 8; ++k) rk[k] = atomicAdd(&lh[sv[k] >> BSH], 1u);
    } else {
#pragma unroll
        for (int k = 0; k < 8; ++k) {
            bool v = (i0 + k) < nloc;
            rk[k] = v ? atomicAdd(&lh[sv[k] >> BSH], 1u) : 0u;
        }
    }
    __syncthreads();
    // shfl-based inclusive scan over NB bucket counts
    int lane = t & 63, w = t >> 6;
    u32 v = (t < NB) ? lh[t] : 0u;
    u32 inc = v;
#pragma unroll
    for (int d = 1; d < 64; d <<= 1) {
        u32 o = __shfl_up(inc, (unsigned)d, 64);
        if (lane >= d) inc += o;
    }
    if (lane == 63) wsum[w] = inc;
    __syncthreads();
    u32 woff = 0;
    for (int i = 0; i < w; ++i) woff += wsum[i];
    inc += woff;
    u32 ex = inc - v;
    if (t < NB) { offsT[(size_t)t * nch + c] = ex; lh[t] = ex; }
    if (t == 0) offsT[(size_t)NB * nch + c] = (u32)nloc;
    __syncthreads();
    // atomic-free placement into LDS: pos = bucket_exclusive + rank
    if (full) {
#pragma unroll
        for (int k = 0; k < 8; ++k) {
            int s = sv[k];
            u32 pos = lh[s >> BSH] + rk[k];
            skey[pos] = ((u32)(s & (BNODES - 1)) << 17) | (u32)dv[k];
            swv[pos] = f32_f16b(wv[k]);          // w in [0,1): fp16, sign bit 0
        }
    } else {
#pragma unroll
        for (int k = 0; k < 8; ++k) {
            if ((i0 + k) < nloc) {
                int s = sv[k];
                u32 pos = lh[s >> BSH] + rk[k];
                skey[pos] = ((u32)(s & (BNODES - 1)) << 17) | (u32)dv[k];
                swv[pos] = f32_f16b(wv[k]);
            }
        }
    }
    __syncthreads();
    // coalesced streamout (tail beyond nloc is never read downstream — garbage ok)
    ((uint4*)(rkey + (size_t)base))[t]        = ((const uint4*)skey)[t];
    ((uint4*)(rkey + (size_t)base))[t + 1024] = ((const uint4*)skey)[t + 1024];
    ((uint4*)(rwh + (size_t)base))[t]         = ((const uint4*)swv)[t];
}

// ---------------- k_nh: runid inverse-map key histogram + reg-cached GEMM ----------------
__global__ __launch_bounds__(512) void k_nh(const u32* __restrict__ rkey,
                                            const u32* __restrict__ offsT,
                                            const float* __restrict__ feat,
                                            const float* __restrict__ kern,
                                            u16* __restrict__ hsb,
                                            u32* __restrict__ nodemeta,
                                            int N, int NB, int nch) {
    __shared__ float skern[FDIM * FDIM];
    __shared__ float sfeat[BNODES * FDIM];
    __shared__ u32 sbase[NCMAX];
    __shared__ u16 runid[RCAP];
    __shared__ u32 lcnt[BNODES];
    __shared__ float lnorm[BNODES];
    __shared__ u32 wsum[8];
    __shared__ u32 ws2[2];
    __shared__ u32 stot;
    int b = blockIdx.x, t = threadIdx.x;
    for (int i = t; i < FDIM * FDIM / 4; i += 512) ((float4*)skern)[i] = ((const float4*)kern)[i];
    int base_n = b << BSH;
    int base_nf = base_n * FDIM;
    int lim = N * FDIM - base_nf; if (lim > BNODES * FDIM) lim = BNODES * FDIM;
    for (int i = t; i < (lim >> 2); i += 512) ((float4*)sfeat)[i] = ((const float4*)(feat + base_nf))[i];
    if (t < BNODES) lcnt[t] = 0u;
    u32 rl = 0u, s0 = 0u;
    if (t < nch) {
        s0 = offsT[(size_t)b * nch + t];             // coalesced row read
        rl = offsT[(size_t)(b + 1) * nch + t] - s0;  // coalesced row read
    }
    int lane = t & 63, w = t >> 6;
    u32 inc = rl;
#pragma unroll
    for (int d = 1; d < 64; d <<= 1) {
        u32 o = __shfl_up(inc, (unsigned)d, 64);
        if (lane >= d) inc += o;
    }
    if (lane == 63) wsum[w] = inc;
    __syncthreads();
    u32 woff = 0;
    for (int i = 0; i < w; ++i) woff += wsum[i];
    inc += woff;
    // inverse map: run r owns records [pl0, pl0+rl) -> runid[]; sbase folds per-run consts
    if (t < nch) {
        u32 pl0 = inc - rl;
        sbase[t] = (u32)t * CHUNK + s0 - pl0;
        u32 p = pl0 < RCAP ? pl0 : RCAP;
        u32 e = pl0 + rl; if (e > RCAP) e = RCAP;
        for (; p < e; ++p) runid[p] = (u16)t;
    }
    if (t == nch - 1) stot = inc;
    __syncthreads();
    u32 tot = stot; if (tot > RCAP) tot = RCAP;
    // histogram: 8 statically-unrolled independent chains
    {
        u32 keyv[8]; bool val[8];
#pragma unroll
        for (int i = 0; i < 8; ++i) {
            u32 g = (u32)t + ((u32)i << 9);
            val[i] = g < tot;
            keyv[i] = 0u;
            if (val[i]) {
                int r = runid[g];
                keyv[i] = rkey[(size_t)(sbase[r] + g)];
            }
        }
#pragma unroll
        for (int i = 0; i < 8; ++i)
            if (val[i]) atomicAdd(&lcnt[keyv[i] >> 17], 1u);
        for (u32 g = (u32)t + 4096u; g < tot; g += 512u) {
            int r = runid[g];
            atomicAdd(&lcnt[rkey[(size_t)(sbase[r] + g)] >> 17], 1u);
        }
    }
    __syncthreads();
    // nodemeta: 4-record-aligned exclusive offsets (16 B ssrec alignment for b128 reads)
    u32 d = 0u, pad = 0u, inc2 = 0u;
    if (t < BNODES) {
        d = lcnt[t];
        pad = (d + 3u) & ~3u;
        inc2 = pad;
    }
    if (t < 128) {
#pragma unroll
        for (int dd = 1; dd < 64; dd <<= 1) {
            u32 o = __shfl_up(inc2, (unsigned)dd, 64);
            if ((t & 63) >= dd) inc2 += o;
        }
        if ((t & 63) == 63) ws2[t >> 6] = inc2;
    }
    __syncthreads();
    if (t < 128) {
        if (t >= 64) inc2 += ws2[0];
        u32 ex = inc2 - pad;
        lnorm[t] = rsqrtf(fmaxf((float)d, 1.0f));
        int n = base_n + t;
        if (n < N) nodemeta[n] = ex | (d << 16);
    }
    __syncthreads();
    // GEMM: skern column cached in 32 registers, sfeat rows as float4
    int f = t & 31, g8 = t >> 5;
    float kc[FDIM];
#pragma unroll
    for (int k = 0; k < FDIM; ++k) kc[k] = skern[k * FDIM + f];
#pragma unroll
    for (int k8 = 0; k8 < 8; ++k8) {
        int nl = g8 * 8 + k8;
        int n = base_n + nl;
        const float4* fr = (const float4*)(sfeat + nl * FDIM);
        float4 rr[8];
#pragma unroll
        for (int q = 0; q < 8; ++q) rr[q] = fr[q];
        float acc = 0.f;
#pragma unroll
        for (int q = 0; q < 8; ++q) {
            acc = fmaf(rr[q].x, kc[4 * q + 0], acc);
            acc = fmaf(rr[q].y, kc[4 * q + 1], acc);
            acc = fmaf(rr[q].z, kc[4 * q + 2], acc);
            acc = fmaf(rr[q].w, kc[4 * q + 3], acc);
        }
        float x = lnorm[nl] * acc;
        u32 u = __float_as_uint(x);
        u = (u + 0x7FFFu + ((u >> 16) & 1u)) >> 16;   // RNE f32 -> bf16
        if (n < N) hsb[(size_t)n * FDIM + f] = (u16)u;
    }
}

// ---------------- k2: packed-u32 ssrec; (512,6) = VGPR cap 85, NO SPILL; 8-wide gather ----------------
// round-4 lesson: __launch_bounds__(512,8) forced VGPR<=64 -> compiler spilled the 8 in-flight
// uint4 h-values to scratch (FETCH +120MB, WRITE +124MB, VALUBusy halved, dur 2x). (512,6)
// gives an ~85-reg budget: 8-wide gather fits; LDS 34.8KB still allows 4 blocks/CU.
__global__ __launch_bounds__(512, 6) void k2(const u32* __restrict__ rkey,
                                             const u16* __restrict__ rwh,
                                             const u32* __restrict__ offsT,
                                             const u32* __restrict__ nodemeta,
                                             const u16* __restrict__ hsb,
                                             const float* __restrict__ bias,
                                             float* __restrict__ out,
                                             int N, int NB, int nch) {
    __shared__ __align__(16) u32 ssrec[SCAP];   // 20 KB packed node-sorted records
    __shared__ u32 sbase[NCMAX];
    __shared__ u16 runid[RCAP];
    __shared__ u32 loff[BNODES];
    __shared__ u32 lcnt[BNODES];
    __shared__ u32 lcur[BNODES];
    __shared__ u32 snode[BNODES];
    __shared__ u32 lbin[128];
    __shared__ u32 wsum[8];
    __shared__ u32 ws2[2];
    __shared__ u32 stot;
    int b = blockIdx.x, t = threadIdx.x;
    int base_n = b << BSH;
    if (t < BNODES) {
        int n = base_n + t;
        u32 m = (n < N) ? nodemeta[n] : 0u;
        loff[t] = m & 0xFFFFu;
        lcnt[t] = m >> 16;
        lcur[t] = m & 0xFFFFu;
    }
    if (t < 128) lbin[t] = 0u;
    u32 rl = 0u, s0 = 0u;
    if (t < nch) {
        s0 = offsT[(size_t)b * nch + t];
        rl = offsT[(size_t)(b + 1) * nch + t] - s0;
    }
    int lane = t & 63, w = t >> 6;
    u32 inc = rl;
#pragma unroll
    for (int d = 1; d < 64; d <<= 1) {
        u32 o = __shfl_up(inc, (unsigned)d, 64);
        if (lane >= d) inc += o;
    }
    if (lane == 63) wsum[w] = inc;
    __syncthreads();
    u32 woff = 0;
    for (int i = 0; i < w; ++i) woff += wsum[i];
    inc += woff;
    if (t < nch) {
        u32 pl0 = inc - rl;
        sbase[t] = (u32)t * CHUNK + s0 - pl0;
        u32 p = pl0 < RCAP ? pl0 : RCAP;
        u32 e = pl0 + rl; if (e > RCAP) e = RCAP;
        for (; p < e; ++p) runid[p] = (u16)t;
    }
    if (t == nch - 1) stot = inc;
    __syncthreads();
    u32 tot = stot; if (tot > RCAP) tot = RCAP;
    // scatter: 8 independent load chains (rkey + rwh), pack to u32, LDS node-sort
    {
        u32 keyv[8], whv[8]; bool val[8];
#pragma unroll
        for (int i = 0; i < 8; ++i) {
            u32 g = (u32)t + ((u32)i << 9);
            val[i] = g < tot;
            keyv[i] = 0u; whv[i] = 0u;
            if (val[i]) {
                int r = runid[g];
                u32 idx = sbase[r] + g;
                keyv[i] = rkey[(size_t)idx];
                whv[i] = rwh[(size_t)idx];
            }
        }
#pragma unroll
        for (int i = 0; i < 8; ++i) {
            if (val[i]) {
                u32 pos = atomicAdd(&lcur[keyv[i] >> 17], 1u);
                if (pos < SCAP) ssrec[pos] = ((keyv[i] & 0x1FFFFu) << 15) | (whv[i] & 0x7FFFu);
            }
        }
        for (u32 g = (u32)t + 4096u; g < tot; g += 512u) {
            int r = runid[g];
            u32 idx = sbase[r] + g;
            u32 key = rkey[(size_t)idx];
            u32 wh = rwh[(size_t)idx];
            u32 pos = atomicAdd(&lcur[key >> 17], 1u);
            if (pos < SCAP) ssrec[pos] = ((key & 0x1FFFFu) << 15) | (wh & 0x7FFFu);
        }
    }
    // degree counting-sort (128 bins) for wave load balance
    if (t < BNODES) {
        u32 len = lcnt[t];
        atomicAdd(&lbin[len > 127u ? 127u : len], 1u);
    }
    __syncthreads();
    u32 bv_ = 0u, binc = 0u;
    if (t < 128) {
        bv_ = lbin[t];
        binc = bv_;
#pragma unroll
        for (int dd = 1; dd < 64; dd <<= 1) {
            u32 o = __shfl_up(binc, (unsigned)dd, 64);
            if ((t & 63) >= dd) binc += o;
        }
        if ((t & 63) == 63) ws2[t >> 6] = binc;
    }
    __syncthreads();
    if (t < 128) {
        if (t >= 64) binc += ws2[0];
        lbin[t] = binc - bv_;                        // exclusive
    }
    __syncthreads();
    if (t < BNODES) {
        u32 len = lcnt[t];
        u32 pos = atomicAdd(&lbin[len > 127u ? 127u : len], 1u);
        snode[pos] = (u32)t;
    }
    __syncthreads();
    // gather: 128 groups of 4 lanes; lane l = features 8l..8l+7; 8 records per 2 b128 LDS reads
    int l = t & 3, g = t >> 2;
    u32 nl = snode[g];
    int n = base_n + (int)nl;
    u32 off = loff[nl];                  // multiple of 4 -> 16 B aligned
    u32 len = lcnt[nl];
    float ns = rsqrtf(fmaxf((float)len, 1.0f));
    const uint4* hp4 = (const uint4*)hsb;           // row n: hp4[n*4 + l]
    float4 bv0 = ((const float4*)bias)[2 * l];
    float4 bv1 = ((const float4*)bias)[2 * l + 1];
    float4 x0 = make_float4(0.f, 0.f, 0.f, 0.f), x1 = make_float4(0.f, 0.f, 0.f, 0.f);
    float4 y0 = make_float4(0.f, 0.f, 0.f, 0.f), y1 = make_float4(0.f, 0.f, 0.f, 0.f);
    u32 j = 0;
    for (; j + 8 <= len; j += 8) {
        uint4 a = *(const uint4*)(ssrec + off + j);        // rec j..j+3
        uint4 c = *(const uint4*)(ssrec + off + j + 4);    // rec j+4..j+7
        uint4 h0 = hp4[(size_t)(a.x >> 15) * 4 + l];
        uint4 h1 = hp4[(size_t)(a.y >> 15) * 4 + l];
        uint4 h2 = hp4[(size_t)(a.z >> 15) * 4 + l];
        uint4 h3 = hp4[(size_t)(a.w >> 15) * 4 + l];
        uint4 h4 = hp4[(size_t)(c.x >> 15) * 4 + l];
        uint4 h5 = hp4[(size_t)(c.y >> 15) * 4 + l];
        uint4 h6 = hp4[(size_t)(c.z >> 15) * 4 + l];
        uint4 h7 = hp4[(size_t)(c.w >> 15) * 4 + l];
        acc8(x0, x1, f16b_f32(a.x & 0x7FFFu), h0);
        acc8(y0, y1, f16b_f32(a.y & 0x7FFFu), h1);
        acc8(x0, x1, f16b_f32(a.z & 0x7FFFu), h2);
        acc8(y0, y1, f16b_f32(a.w & 0x7FFFu), h3);
        acc8(x0, x1, f16b_f32(c.x & 0x7FFFu), h4);
        acc8(y0, y1, f16b_f32(c.y & 0x7FFFu), h5);
        acc8(x0, x1, f16b_f32(c.z & 0x7FFFu), h6);
        acc8(y0, y1, f16b_f32(c.w & 0x7FFFu), h7);
    }
    for (; j + 4 <= len; j += 4) {
        uint4 a = *(const uint4*)(ssrec + off + j);
        uint4 h0 = hp4[(size_t)(a.x >> 15) * 4 + l];
        uint4 h1 = hp4[(size_t)(a.y >> 15) * 4 + l];
        uint4 h2 = hp4[(size_t)(a.z >> 15) * 4 + l];
        uint4 h3 = hp4[(size_t)(a.w >> 15) * 4 + l];
        acc8(x0, x1, f16b_f32(a.x & 0x7FFFu), h0);
        acc8(y0, y1, f16b_f32(a.y & 0x7FFFu), h1);
        acc8(x0, x1, f16b_f32(a.z & 0x7FFFu), h2);
        acc8(y0, y1, f16b_f32(a.w & 0x7FFFu), h3);
    }
    for (; j < len; ++j) {
        u32 q = ssrec[off + j];
        uint4 h = hp4[(size_t)(q >> 15) * 4 + l];
        acc8(x0, x1, f16b_f32(q & 0x7FFFu), h);
    }
    if (n < N) {
        float4 r0, r1;
        r0.x = fmaf(ns, x0.x + y0.x, bv0.x);
        r0.y = fmaf(ns, x0.y + y0.y, bv0.y);
        r0.z = fmaf(ns, x0.z + y0.z, bv0.z);
        r0.w = fmaf(ns, x0.w + y0.w, bv0.w);
        r1.x = fmaf(ns, x1.x + y1.x, bv1.x);
        r1.y = fmaf(ns, x1.y + y1.y, bv1.y);
        r1.z = fmaf(ns, x1.z + y1.z, bv1.z);
        r1.w = fmaf(ns, x1.w + y1.w, bv1.w);
        ((float4*)(out + (size_t)n * FDIM))[2 * l] = r0;
        ((float4*)(out + (size_t)n * FDIM))[2 * l + 1] = r1;
    }
}

extern "C" void kernel_launch(void* const* d_in, const int* in_sizes, int n_in,
                              void* d_out, int out_size, void* d_ws, size_t ws_size,
                              hipStream_t stream) {
    const float* feat = (const float*)d_in[0];
    const int*   srcs = (const int*)d_in[1];
    const int*   dsts = (const int*)d_in[2];
    const float* ew   = (const float*)d_in[3];
    const float* kern = (const float*)d_in[4];
    const float* bias = (const float*)d_in[5];
    float* out = (float*)d_out;

    int N = in_sizes[0] / FDIM;
    int E = in_sizes[1];
    int NB = (N + BNODES - 1) >> BSH;        // 782 for N=100000; <= NBMAX
    int nchunks = (E + CHUNK - 1) / CHUNK;   // 391; <= NCMAX

    // workspace layout (~27 MB)
    char* w = (char*)d_ws;
    u16* hsb      = (u16*)w;   w += (((size_t)N * FDIM * sizeof(u16) + 15) & ~15ull);     // 6.4 MB
    u32* rkey     = (u32*)w;   w += (size_t)nchunks * CHUNK * sizeof(u32);                // 12.8 MB
    u16* rwh      = (u16*)w;   w += (((size_t)nchunks * CHUNK * sizeof(u16) + 15) & ~15ull); // 6.4 MB
    u32* offsT    = (u32*)w;   w += (size_t)(NB + 1) * nchunks * sizeof(u32);             // 1.2 MB
    u32* nodemeta = (u32*)w;   w += (size_t)N * sizeof(u32);                              // 0.4 MB

    k1b<<<nchunks, 1024, 0, stream>>>(srcs, dsts, ew, offsT, rkey, rwh, E, NB, nchunks);
    k_nh<<<NB, 512, 0, stream>>>(rkey, offsT, feat, kern, hsb, nodemeta, N, NB, nchunks);
    k2<<<NB, 512, 0, stream>>>(rkey, rwh, offsT, nodemeta, hsb, bias, out, N, NB, nchunks);
}

// Round 6
// 169.875 us; speedup vs baseline: 1.3337x; 1.0841x over previous
//
#include <hip/hip_runtime.h>
#include <hip/hip_fp16.h>

#define FDIM 32
#define BSH 7                 // 128 nodes per bucket
#define BNODES 128
#define NBMAX 1024            // max buckets (N <= 131072)
#define CHUNK 8192            // edges per partition chunk (391 chunks at E=3.2M)
#define NCMAX 512             // max chunks (E <= 4.19M)
#define RCAP 4608             // per-bucket record cap (mean 4096, +8 sigma)
#define SCAP 5120             // ssrec cap: RCAP + 128*4-alignment padding headroom

typedef unsigned int u32;
typedef unsigned short u16;

#define BFLO(u) __uint_as_float((u) << 16)
#define BFHI(u) __uint_as_float((u) & 0xFFFF0000u)

union HCV { __half h; u16 u; };
__device__ __forceinline__ u16 f32_f16b(float f) { HCV c; c.h = __float2half(f); return c.u; }
__device__ __forceinline__ float f16b_f32(u32 b) { HCV c; c.u = (u16)b; return __half2float(c.h); }

__device__ __forceinline__ void acc8(float4& p0, float4& p1, float w, uint4 h) {
    p0.x = fmaf(w, BFLO(h.x), p0.x);
    p0.y = fmaf(w, BFHI(h.x), p0.y);
    p0.z = fmaf(w, BFLO(h.y), p0.z);
    p0.w = fmaf(w, BFHI(h.y), p0.w);
    p1.x = fmaf(w, BFLO(h.z), p1.x);
    p1.y = fmaf(w, BFHI(h.z), p1.y);
    p1.z = fmaf(w, BFLO(h.w), p1.z);
    p1.w = fmaf(w, BFHI(h.w), p1.w);
}

// ---------------- k1b: partition; LDS-staged scatter -> fully-coalesced streamout ----------------
__global__ __launch_bounds__(1024, 8) void k1b(const int* __restrict__ srcs,
                                               const int* __restrict__ dsts,
                                               const float* __restrict__ ew,
                                               u32* __restrict__ offsT,
                                               u32* __restrict__ rkey,
                                               u16* __restrict__ rwh,
                                               int E, int NB, int nch) {
    __shared__ __align__(16) u32 skey[CHUNK];   // 32 KB
    __shared__ __align__(16) u16 swv[CHUNK];    // 16 KB
    __shared__ u32 lh[NBMAX];                   // 4 KB
    __shared__ u32 wsum[16];
    int t = threadIdx.x, c = blockIdx.x;
    int base = c * CHUNK;
    int end = base + CHUNK; if (end > E) end = E;
    int nloc = end - base;
    int i0 = t * 8;
    bool full = (i0 + 8 <= nloc);
    int sv[8], dv[8];
    float wv[8];
    u32 rk[8];
    // hoist ALL loads before the histogram (latency overlap)
    if (full) {
        int4 a  = ((const int4*)(srcs + base))[t * 2];
        int4 b2 = ((const int4*)(srcs + base))[t * 2 + 1];
        int4 d0 = ((const int4*)(dsts + base))[t * 2];
        int4 d1 = ((const int4*)(dsts + base))[t * 2 + 1];
        float4 w0 = ((const float4*)(ew + base))[t * 2];
        float4 w1 = ((const float4*)(ew + base))[t * 2 + 1];
        sv[0]=a.x; sv[1]=a.y; sv[2]=a.z; sv[3]=a.w; sv[4]=b2.x; sv[5]=b2.y; sv[6]=b2.z; sv[7]=b2.w;
        dv[0]=d0.x; dv[1]=d0.y; dv[2]=d0.z; dv[3]=d0.w; dv[4]=d1.x; dv[5]=d1.y; dv[6]=d1.z; dv[7]=d1.w;
        wv[0]=w0.x; wv[1]=w0.y; wv[2]=w0.z; wv[3]=w0.w; wv[4]=w1.x; wv[5]=w1.y; wv[6]=w1.z; wv[7]=w1.w;
    } else {
#pragma unroll
        for (int k = 0; k < 8; ++k) {
            int i = i0 + k;
            bool v = i < nloc;
            sv[k] = v ? srcs[base + i] : 0;
            dv[k] = v ? dsts[base + i] : 0;
            wv[k] = v ? ew[base + i] : 0.f;
        }
    }
    for (int i = t; i < NB; i += 1024) lh[i] = 0u;
    __syncthreads();
    if (full) {
#pragma unroll
        for (int k = 0; k < 8; ++k) rk[k] = atomicAdd(&lh[sv[k] >> BSH], 1u);
    } else {
#pragma unroll
        for (int k = 0; k < 8; ++k) {
            bool v = (i0 + k) < nloc;
            rk[k] = v ? atomicAdd(&lh[sv[k] >> BSH], 1u) : 0u;
        }
    }
    __syncthreads();
    // shfl-based inclusive scan over NB bucket counts
    int lane = t & 63, w = t >> 6;
    u32 v = (t < NB) ? lh[t] : 0u;
    u32 inc = v;
#pragma unroll
    for (int d = 1; d < 64; d <<= 1) {
        u32 o = __shfl_up(inc, (unsigned)d, 64);
        if (lane >= d) inc += o;
    }
    if (lane == 63) wsum[w] = inc;
    __syncthreads();
    u32 woff = 0;
    for (int i = 0; i < w; ++i) woff += wsum[i];
    inc += woff;
    u32 ex = inc - v;
    if (t < NB) { offsT[(size_t)t * nch + c] = ex; lh[t] = ex; }
    if (t == 0) offsT[(size_t)NB * nch + c] = (u32)nloc;
    __syncthreads();
    // atomic-free placement into LDS: pos = bucket_exclusive + rank
    if (full) {
#pragma unroll
        for (int k = 0; k < 8; ++k) {
            int s = sv[k];
            u32 pos = lh[s >> BSH] + rk[k];
            skey[pos] = ((u32)(s & (BNODES - 1)) << 17) | (u32)dv[k];
            swv[pos] = f32_f16b(wv[k]);          // w in [0,1): fp16, sign bit 0
        }
    } else {
#pragma unroll
        for (int k = 0; k < 8; ++k) {
            if ((i0 + k) < nloc) {
                int s = sv[k];
                u32 pos = lh[s >> BSH] + rk[k];
                skey[pos] = ((u32)(s & (BNODES - 1)) << 17) | (u32)dv[k];
                swv[pos] = f32_f16b(wv[k]);
            }
        }
    }
    __syncthreads();
    // coalesced streamout (tail beyond nloc is never read downstream — garbage ok)
    ((uint4*)(rkey + (size_t)base))[t]        = ((const uint4*)skey)[t];
    ((uint4*)(rkey + (size_t)base))[t + 1024] = ((const uint4*)skey)[t + 1024];
    ((uint4*)(rwh + (size_t)base))[t]         = ((const uint4*)swv)[t];
}

// ---------------- k_nh: runid inverse-map key histogram + reg-cached GEMM ----------------
__global__ __launch_bounds__(512) void k_nh(const u32* __restrict__ rkey,
                                            const u32* __restrict__ offsT,
                                            const float* __restrict__ feat,
                                            const float* __restrict__ kern,
                                            u16* __restrict__ hsb,
                                            u32* __restrict__ nodemeta,
                                            int N, int NB, int nch) {
    __shared__ float skern[FDIM * FDIM];
    __shared__ float sfeat[BNODES * FDIM];
    __shared__ u32 sbase[NCMAX];
    __shared__ u16 runid[RCAP];
    __shared__ u32 lcnt[BNODES];
    __shared__ float lnorm[BNODES];
    __shared__ u32 wsum[8];
    __shared__ u32 ws2[2];
    __shared__ u32 stot;
    int b = blockIdx.x, t = threadIdx.x;
    for (int i = t; i < FDIM * FDIM / 4; i += 512) ((float4*)skern)[i] = ((const float4*)kern)[i];
    int base_n = b << BSH;
    int base_nf = base_n * FDIM;
    int lim = N * FDIM - base_nf; if (lim > BNODES * FDIM) lim = BNODES * FDIM;
    for (int i = t; i < (lim >> 2); i += 512) ((float4*)sfeat)[i] = ((const float4*)(feat + base_nf))[i];
    if (t < BNODES) lcnt[t] = 0u;
    u32 rl = 0u, s0 = 0u;
    if (t < nch) {
        s0 = offsT[(size_t)b * nch + t];             // coalesced row read
        rl = offsT[(size_t)(b + 1) * nch + t] - s0;  // coalesced row read
    }
    int lane = t & 63, w = t >> 6;
    u32 inc = rl;
#pragma unroll
    for (int d = 1; d < 64; d <<= 1) {
        u32 o = __shfl_up(inc, (unsigned)d, 64);
        if (lane >= d) inc += o;
    }
    if (lane == 63) wsum[w] = inc;
    __syncthreads();
    u32 woff = 0;
    for (int i = 0; i < w; ++i) woff += wsum[i];
    inc += woff;
    // inverse map: run r owns records [pl0, pl0+rl) -> runid[]; sbase folds per-run consts
    if (t < nch) {
        u32 pl0 = inc - rl;
        sbase[t] = (u32)t * CHUNK + s0 - pl0;
        u32 p = pl0 < RCAP ? pl0 : RCAP;
        u32 e = pl0 + rl; if (e > RCAP) e = RCAP;
        for (; p < e; ++p) runid[p] = (u16)t;
    }
    if (t == nch - 1) stot = inc;
    __syncthreads();
    u32 tot = stot; if (tot > RCAP) tot = RCAP;
    // histogram: 8 statically-unrolled independent chains
    {
        u32 keyv[8]; bool val[8];
#pragma unroll
        for (int i = 0; i < 8; ++i) {
            u32 g = (u32)t + ((u32)i << 9);
            val[i] = g < tot;
            keyv[i] = 0u;
            if (val[i]) {
                int r = runid[g];
                keyv[i] = rkey[(size_t)(sbase[r] + g)];
            }
        }
#pragma unroll
        for (int i = 0; i < 8; ++i)
            if (val[i]) atomicAdd(&lcnt[keyv[i] >> 17], 1u);
        for (u32 g = (u32)t + 4096u; g < tot; g += 512u) {
            int r = runid[g];
            atomicAdd(&lcnt[rkey[(size_t)(sbase[r] + g)] >> 17], 1u);
        }
    }
    __syncthreads();
    // nodemeta: 4-record-aligned exclusive offsets (16 B ssrec alignment for b128 reads)
    u32 d = 0u, pad = 0u, inc2 = 0u;
    if (t < BNODES) {
        d = lcnt[t];
        pad = (d + 3u) & ~3u;
        inc2 = pad;
    }
    if (t < 128) {
#pragma unroll
        for (int dd = 1; dd < 64; dd <<= 1) {
            u32 o = __shfl_up(inc2, (unsigned)dd, 64);
            if ((t & 63) >= dd) inc2 += o;
        }
        if ((t & 63) == 63) ws2[t >> 6] = inc2;
    }
    __syncthreads();
    if (t < 128) {
        if (t >= 64) inc2 += ws2[0];
        u32 ex = inc2 - pad;
        lnorm[t] = rsqrtf(fmaxf((float)d, 1.0f));
        int n = base_n + t;
        if (n < N) nodemeta[n] = ex | (d << 16);
    }
    __syncthreads();
    // GEMM: skern column cached in 32 registers, sfeat rows as float4
    int f = t & 31, g8 = t >> 5;
    float kc[FDIM];
#pragma unroll
    for (int k = 0; k < FDIM; ++k) kc[k] = skern[k * FDIM + f];
#pragma unroll
    for (int k8 = 0; k8 < 8; ++k8) {
        int nl = g8 * 8 + k8;
        int n = base_n + nl;
        const float4* fr = (const float4*)(sfeat + nl * FDIM);
        float4 rr[8];
#pragma unroll
        for (int q = 0; q < 8; ++q) rr[q] = fr[q];
        float acc = 0.f;
#pragma unroll
        for (int q = 0; q < 8; ++q) {
            acc = fmaf(rr[q].x, kc[4 * q + 0], acc);
            acc = fmaf(rr[q].y, kc[4 * q + 1], acc);
            acc = fmaf(rr[q].z, kc[4 * q + 2], acc);
            acc = fmaf(rr[q].w, kc[4 * q + 3], acc);
        }
        float x = lnorm[nl] * acc;
        u32 u = __float_as_uint(x);
        u = (u + 0x7FFFu + ((u >> 16) & 1u)) >> 16;   // RNE f32 -> bf16
        if (n < N) hsb[(size_t)n * FDIM + f] = (u16)u;
    }
}

// ---------------- k2: packed-u32 ssrec; PLAIN launch_bounds (no min-waves) ----------------
// round-4/5 lesson: any min-waves arg (8 or 6) pins the VGPR allocator to 32-40 regs and the
// 8-wide gather spills ~22 dwords/thread to scratch (WRITE +35MB, FETCH +47MB, dur 1.5-2.5x).
// Plain (512) allocated 44 regs with ZERO spill in round 3. LDS 34.8KB still -> 4 blocks/CU.
__global__ __launch_bounds__(512) void k2(const u32* __restrict__ rkey,
                                          const u16* __restrict__ rwh,
                                          const u32* __restrict__ offsT,
                                          const u32* __restrict__ nodemeta,
                                          const u16* __restrict__ hsb,
                                          const float* __restrict__ bias,
                                          float* __restrict__ out,
                                          int N, int NB, int nch) {
    __shared__ __align__(16) u32 ssrec[SCAP];   // 20 KB packed node-sorted records
    __shared__ u32 sbase[NCMAX];
    __shared__ u16 runid[RCAP];
    __shared__ u32 loff[BNODES];
    __shared__ u32 lcnt[BNODES];
    __shared__ u32 lcur[BNODES];
    __shared__ u32 snode[BNODES];
    __shared__ u32 lbin[128];
    __shared__ u32 wsum[8];
    __shared__ u32 ws2[2];
    __shared__ u32 stot;
    int b = blockIdx.x, t = threadIdx.x;
    int base_n = b << BSH;
    if (t < BNODES) {
        int n = base_n + t;
        u32 m = (n < N) ? nodemeta[n] : 0u;
        loff[t] = m & 0xFFFFu;
        lcnt[t] = m >> 16;
        lcur[t] = m & 0xFFFFu;
    }
    if (t < 128) lbin[t] = 0u;
    u32 rl = 0u, s0 = 0u;
    if (t < nch) {
        s0 = offsT[(size_t)b * nch + t];
        rl = offsT[(size_t)(b + 1) * nch + t] - s0;
    }
    int lane = t & 63, w = t >> 6;
    u32 inc = rl;
#pragma unroll
    for (int d = 1; d < 64; d <<= 1) {
        u32 o = __shfl_up(inc, (unsigned)d, 64);
        if (lane >= d) inc += o;
    }
    if (lane == 63) wsum[w] = inc;
    __syncthreads();
    u32 woff = 0;
    for (int i = 0; i < w; ++i) woff += wsum[i];
    inc += woff;
    if (t < nch) {
        u32 pl0 = inc - rl;
        sbase[t] = (u32)t * CHUNK + s0 - pl0;
        u32 p = pl0 < RCAP ? pl0 : RCAP;
        u32 e = pl0 + rl; if (e > RCAP) e = RCAP;
        for (; p < e; ++p) runid[p] = (u16)t;
    }
    if (t == nch - 1) stot = inc;
    __syncthreads();
    u32 tot = stot; if (tot > RCAP) tot = RCAP;
    // scatter: 8 independent load chains (rkey + rwh), pack to u32, LDS node-sort
    {
        u32 keyv[8], whv[8]; bool val[8];
#pragma unroll
        for (int i = 0; i < 8; ++i) {
            u32 g = (u32)t + ((u32)i << 9);
            val[i] = g < tot;
            keyv[i] = 0u; whv[i] = 0u;
            if (val[i]) {
                int r = runid[g];
                u32 idx = sbase[r] + g;
                keyv[i] = rkey[(size_t)idx];
                whv[i] = rwh[(size_t)idx];
            }
        }
#pragma unroll
        for (int i = 0; i < 8; ++i) {
            if (val[i]) {
                u32 pos = atomicAdd(&lcur[keyv[i] >> 17], 1u);
                if (pos < SCAP) ssrec[pos] = ((keyv[i] & 0x1FFFFu) << 15) | (whv[i] & 0x7FFFu);
            }
        }
        for (u32 g = (u32)t + 4096u; g < tot; g += 512u) {
            int r = runid[g];
            u32 idx = sbase[r] + g;
            u32 key = rkey[(size_t)idx];
            u32 wh = rwh[(size_t)idx];
            u32 pos = atomicAdd(&lcur[key >> 17], 1u);
            if (pos < SCAP) ssrec[pos] = ((key & 0x1FFFFu) << 15) | (wh & 0x7FFFu);
        }
    }
    // degree counting-sort (128 bins) for wave load balance
    if (t < BNODES) {
        u32 len = lcnt[t];
        atomicAdd(&lbin[len > 127u ? 127u : len], 1u);
    }
    __syncthreads();
    u32 bv_ = 0u, binc = 0u;
    if (t < 128) {
        bv_ = lbin[t];
        binc = bv_;
#pragma unroll
        for (int dd = 1; dd < 64; dd <<= 1) {
            u32 o = __shfl_up(binc, (unsigned)dd, 64);
            if ((t & 63) >= dd) binc += o;
        }
        if ((t & 63) == 63) ws2[t >> 6] = binc;
    }
    __syncthreads();
    if (t < 128) {
        if (t >= 64) binc += ws2[0];
        lbin[t] = binc - bv_;                        // exclusive
    }
    __syncthreads();
    if (t < BNODES) {
        u32 len = lcnt[t];
        u32 pos = atomicAdd(&lbin[len > 127u ? 127u : len], 1u);
        snode[pos] = (u32)t;
    }
    __syncthreads();
    // gather: 128 groups of 4 lanes; lane l = features 8l..8l+7; 8 records per 2 b128 LDS reads
    int l = t & 3, g = t >> 2;
    u32 nl = snode[g];
    int n = base_n + (int)nl;
    u32 off = loff[nl];                  // multiple of 4 -> 16 B aligned
    u32 len = lcnt[nl];
    float ns = rsqrtf(fmaxf((float)len, 1.0f));
    const uint4* hp4 = (const uint4*)hsb;           // row n: hp4[n*4 + l]
    float4 bv0 = ((const float4*)bias)[2 * l];
    float4 bv1 = ((const float4*)bias)[2 * l + 1];
    float4 x0 = make_float4(0.f, 0.f, 0.f, 0.f), x1 = make_float4(0.f, 0.f, 0.f, 0.f);
    float4 y0 = make_float4(0.f, 0.f, 0.f, 0.f), y1 = make_float4(0.f, 0.f, 0.f, 0.f);
    u32 j = 0;
    for (; j + 8 <= len; j += 8) {
        uint4 a = *(const uint4*)(ssrec + off + j);        // rec j..j+3
        uint4 c = *(const uint4*)(ssrec + off + j + 4);    // rec j+4..j+7
        uint4 h0 = hp4[(size_t)(a.x >> 15) * 4 + l];
        uint4 h1 = hp4[(size_t)(a.y >> 15) * 4 + l];
        uint4 h2 = hp4[(size_t)(a.z >> 15) * 4 + l];
        uint4 h3 = hp4[(size_t)(a.w >> 15) * 4 + l];
        uint4 h4 = hp4[(size_t)(c.x >> 15) * 4 + l];
        uint4 h5 = hp4[(size_t)(c.y >> 15) * 4 + l];
        uint4 h6 = hp4[(size_t)(c.z >> 15) * 4 + l];
        uint4 h7 = hp4[(size_t)(c.w >> 15) * 4 + l];
        acc8(x0, x1, f16b_f32(a.x & 0x7FFFu), h0);
        acc8(y0, y1, f16b_f32(a.y & 0x7FFFu), h1);
        acc8(x0, x1, f16b_f32(a.z & 0x7FFFu), h2);
        acc8(y0, y1, f16b_f32(a.w & 0x7FFFu), h3);
        acc8(x0, x1, f16b_f32(c.x & 0x7FFFu), h4);
        acc8(y0, y1, f16b_f32(c.y & 0x7FFFu), h5);
        acc8(x0, x1, f16b_f32(c.z & 0x7FFFu), h6);
        acc8(y0, y1, f16b_f32(c.w & 0x7FFFu), h7);
    }
    for (; j + 4 <= len; j += 4) {
        uint4 a = *(const uint4*)(ssrec + off + j);
        uint4 h0 = hp4[(size_t)(a.x >> 15) * 4 + l];
        uint4 h1 = hp4[(size_t)(a.y >> 15) * 4 + l];
        uint4 h2 = hp4[(size_t)(a.z >> 15) * 4 + l];
        uint4 h3 = hp4[(size_t)(a.w >> 15) * 4 + l];
        acc8(x0, x1, f16b_f32(a.x & 0x7FFFu), h0);
        acc8(y0, y1, f16b_f32(a.y & 0x7FFFu), h1);
        acc8(x0, x1, f16b_f32(a.z & 0x7FFFu), h2);
        acc8(y0, y1, f16b_f32(a.w & 0x7FFFu), h3);
    }
    for (; j < len; ++j) {
        u32 q = ssrec[off + j];
        uint4 h = hp4[(size_t)(q >> 15) * 4 + l];
        acc8(x0, x1, f16b_f32(q & 0x7FFFu), h);
    }
    if (n < N) {
        float4 r0, r1;
        r0.x = fmaf(ns, x0.x + y0.x, bv0.x);
        r0.y = fmaf(ns, x0.y + y0.y, bv0.y);
        r0.z = fmaf(ns, x0.z + y0.z, bv0.z);
        r0.w = fmaf(ns, x0.w + y0.w, bv0.w);
        r1.x = fmaf(ns, x1.x + y1.x, bv1.x);
        r1.y = fmaf(ns, x1.y + y1.y, bv1.y);
        r1.z = fmaf(ns, x1.z + y1.z, bv1.z);
        r1.w = fmaf(ns, x1.w + y1.w, bv1.w);
        ((float4*)(out + (size_t)n * FDIM))[2 * l] = r0;
        ((float4*)(out + (size_t)n * FDIM))[2 * l + 1] = r1;
    }
}

extern "C" void kernel_launch(void* const* d_in, const int* in_sizes, int n_in,
                              void* d_out, int out_size, void* d_ws, size_t ws_size,
                              hipStream_t stream) {
    const float* feat = (const float*)d_in[0];
    const int*   srcs = (const int*)d_in[1];
    const int*   dsts = (const int*)d_in[2];
    const float* ew   = (const float*)d_in[3];
    const float* kern = (const float*)d_in[4];
    const float* bias = (const float*)d_in[5];
    float* out = (float*)d_out;

    int N = in_sizes[0] / FDIM;
    int E = in_sizes[1];
    int NB = (N + BNODES - 1) >> BSH;        // 782 for N=100000; <= NBMAX
    int nchunks = (E + CHUNK - 1) / CHUNK;   // 391; <= NCMAX

    // workspace layout (~27 MB)
    char* w = (char*)d_ws;
    u16* hsb      = (u16*)w;   w += (((size_t)N * FDIM * sizeof(u16) + 15) & ~15ull);     // 6.4 MB
    u32* rkey     = (u32*)w;   w += (size_t)nchunks * CHUNK * sizeof(u32);                // 12.8 MB
    u16* rwh      = (u16*)w;   w += (((size_t)nchunks * CHUNK * sizeof(u16) + 15) & ~15ull); // 6.4 MB
    u32* offsT    = (u32*)w;   w += (size_t)(NB + 1) * nchunks * sizeof(u32);             // 1.2 MB
    u32* nodemeta = (u32*)w;   w += (size_t)N * sizeof(u32);                              // 0.4 MB

    k1b<<<nchunks, 1024, 0, stream>>>(srcs, dsts, ew, offsT, rkey, rwh, E, NB, nchunks);
    k_nh<<<NB, 512, 0, stream>>>(rkey, offsT, feat, kern, hsb, nodemeta, N, NB, nchunks);
    k2<<<NB, 512, 0, stream>>>(rkey, rwh, offsT, nodemeta, hsb, bias, out, N, NB, nchunks);
}